// Round 1
// 184.363 us; speedup vs baseline: 1.0470x; 1.0470x over previous
//
#include <hip/hip_runtime.h>
#include <hip/hip_bf16.h>
#include <math.h>

#define NROW 4096
#define DIM  1024

typedef short v8s __attribute__((ext_vector_type(8)));
typedef float v4f __attribute__((ext_vector_type(4)));

#define GLD16(src, dst) __builtin_amdgcn_global_load_lds( \
    (const __attribute__((address_space(1))) void*)(src), \
    (__attribute__((address_space(3))) void*)(dst), 16, 0, 0)

__device__ __forceinline__ ushort f2bf(float f) {
    __hip_bfloat16 h = __float2bfloat16(f);
    union { __hip_bfloat16 h; ushort u; } x; x.h = h; return x.u;
}
__device__ __forceinline__ ushort4 cvt4(float4 a) {
    ushort4 r; r.x = f2bf(a.x); r.y = f2bf(a.y); r.z = f2bf(a.z); r.w = f2bf(a.w);
    return r;
}

// ---------------------------------------------------------------- merged row stats + W->bf16
// blocks [0,1024): rowstats on vecs rows (4/block) + bf16 shadow repack.
// blocks [1024,1280): W rows -> bf16 shadow (in place, second half of fp32 row).
__global__ __launch_bounds__(256) void k_stats(
    const float* __restrict__ vecs, const float* __restrict__ mass,
    const float* __restrict__ hops, const int* __restrict__ alive,
    const int* __restrict__ is_photon, const float* __restrict__ wci,
    const float* __restrict__ wcj, const float* __restrict__ logc,
    const float* __restrict__ logG, const float* __restrict__ bconf,
    const float* __restrict__ W,
    double* __restrict__ s_i, double* __restrict__ s_j,
    float* __restrict__ rowAtt, float* __restrict__ rowRep,
    float* __restrict__ massF, int* __restrict__ flags,
    float* __restrict__ rownorm)
{
    const int t = threadIdx.x;
    const int wid = t >> 6, lane = t & 63;

    if (blockIdx.x >= NROW / 4) {                  // ---- W convert part
        const int row = (blockIdx.x - NROW / 4) * 4 + wid;
        const float* wr = W + (size_t)row * DIM;
        ushort4 uc[4];
        #pragma unroll
        for (int q = 0; q < 4; ++q)
            uc[q] = cvt4(*(const float4*)&wr[lane * 4 + q * 256]);
        __syncthreads();
        ushort* wb = (ushort*)W + (size_t)row * 2048 + 1024;
        #pragma unroll
        for (int q = 0; q < 4; ++q)
            *(ushort4*)&wb[lane * 4 + q * 256] = uc[q];
        return;
    }

    const int row = blockIdx.x * 4 + wid;
    const float* vr = vecs + (size_t)row * DIM;
    double di = 0.0, dj = 0.0, ss = 0.0;
    ushort4 uc[4];
    #pragma unroll
    for (int q = 0; q < 4; ++q) {
        int base = lane * 4 + q * 256;             // coalesced: 64 lanes x 16B contiguous
        float4 pv = *(const float4*)&vr[base];
        float4 pi = *(const float4*)&wci[base];
        float4 pj = *(const float4*)&wcj[base];
        di += (double)pv.x * pi.x + (double)pv.y * pi.y + (double)pv.z * pi.z + (double)pv.w * pi.w;
        dj += (double)pv.x * pj.x + (double)pv.y * pj.y + (double)pv.z * pj.z + (double)pv.w * pj.w;
        ss += (double)pv.x * pv.x + (double)pv.y * pv.y + (double)pv.z * pv.z + (double)pv.w * pv.w;
        uc[q] = cvt4(pv);
    }
    __syncthreads();   // all fp32 reads drained before overwriting second halves
    ushort* vb = (ushort*)vecs + (size_t)row * 2048 + 1024;   // bf16 shadow of this row
    #pragma unroll
    for (int q = 0; q < 4; ++q)
        *(ushort4*)&vb[lane * 4 + q * 256] = uc[q];
    #pragma unroll
    for (int off = 32; off > 0; off >>= 1) {
        di += __shfl_down(di, off);
        dj += __shfl_down(dj, off);
        ss += __shfl_down(ss, off);
    }
    if (lane == 0) {
        double c  = fmax(exp((double)logc[0]), 1e-6);
        double G  = exp((double)logG[0]);
        double dl = (double)hops[row] / c;
        double lam = (is_photon[row] != 0) ? 1.0 : exp(-dl);
        double rs  = fmax(dl, 0.1);
        double cd  = (dl <= 1.0) ? 1.0 : exp(-dl + 1.0);
        double m   = (double)mass[row];
        s_i[row] = di;
        s_j[row] = dj + (double)bconf[0];                     // b_conf folded here
        rowAtt[row] = (float)(lam * G * m / (rs * rs) * cd);  // * m_j * (0.5+0.5R)
        rowRep[row] = (float)(-lam * m);                      // * conflict * m_j
        massF[row]  = (float)m;
        flags[row]  = ((alive[row] != 0) ? 1 : 0) | ((sqrt(ss) < 1e-8) ? 2 : 0);
        rownorm[row] = 0.0f;                                  // init for k_proj atomics
    }
}

// ---------------------------------------------------------------- v = vecs @ W^T + b
// 64x64 tiles, BK=64 -> grid (16,64) = 1024 blocks (was 256 = 1 block/CU!).
// LDS 16 KB, low VGPR -> ~6 blocks/CU resident. XOR chunk-swizzle: LDS dest
// linear (global_load_lds requirement), global source chunk ^= row&7,
// ds_read chunk ^= row&7 (involution) -> 2-way bank alias (free).
__global__ __launch_bounds__(256) void k_proj(
    const float* __restrict__ A, const float* __restrict__ B,
    const float* __restrict__ bias, ushort* __restrict__ vout,
    float* __restrict__ rownorm)
{
    __shared__ ushort As[64 * 64], Bs[64 * 64];
    const int t = threadIdx.x;
    const int m0 = blockIdx.y * 64, n0 = blockIdx.x * 64;
    const int wid = t >> 6, lane = t & 63;
    const int wm = wid >> 1, wn = wid & 1;
    const int quad = lane >> 4, l16 = lane & 15;
    const ushort* Ab = (const ushort*)A;   // bf16 shadow: row r at r*2048+1024
    const ushort* Bb = (const ushort*)B;
    const int sr = t >> 3;                 // staging row within 32-row round
    const int sc = t & 7;                  // staging 16B chunk
    v4f acc[2][2];
    #pragma unroll
    for (int i = 0; i < 2; i++)
        #pragma unroll
        for (int j = 0; j < 2; j++) acc[i][j] = (v4f){0.f, 0.f, 0.f, 0.f};

    for (int k0 = 0; k0 < DIM; k0 += 64) {
        #pragma unroll
        for (int p = 0; p < 2; ++p) {
            int r = p * 32 + sr;
            int ksw = ((sc ^ (r & 7)) * 8);
            GLD16(&Ab[(size_t)(m0 + r) * 2048 + 1024 + k0 + ksw], &As[p * 2048 + wid * 512]);
            GLD16(&Bb[(size_t)(n0 + r) * 2048 + 1024 + k0 + ksw], &Bs[p * 2048 + wid * 512]);
        }
        __syncthreads();
        #pragma unroll
        for (int ks = 0; ks < 2; ++ks) {
            v8s af[2], bfr[2];
            #pragma unroll
            for (int mi = 0; mi < 2; mi++) {
                int row = wm * 32 + mi * 16 + l16;
                af[mi] = *(const v8s*)&As[row * 64 + (((ks * 4 + quad) ^ (l16 & 7)) * 8)];
            }
            #pragma unroll
            for (int ni = 0; ni < 2; ni++) {
                int row = wn * 32 + ni * 16 + l16;
                bfr[ni] = *(const v8s*)&Bs[row * 64 + (((ks * 4 + quad) ^ (l16 & 7)) * 8)];
            }
            #pragma unroll
            for (int mi = 0; mi < 2; mi++)
                #pragma unroll
                for (int ni = 0; ni < 2; ni++)
                    acc[mi][ni] = __builtin_amdgcn_mfma_f32_16x16x32_bf16(af[mi], bfr[ni], acc[mi][ni], 0, 0, 0);
        }
        __syncthreads();
    }
    float bcol[2];
    #pragma unroll
    for (int ni = 0; ni < 2; ni++) bcol[ni] = bias[n0 + wn * 32 + ni * 16 + l16];
    #pragma unroll
    for (int mi = 0; mi < 2; mi++)
        #pragma unroll
        for (int r = 0; r < 4; r++) {
            int row = m0 + wm * 32 + mi * 16 + quad * 4 + r;
            float ss = 0.0f;
            #pragma unroll
            for (int ni = 0; ni < 2; ni++) {
                int col = n0 + wn * 32 + ni * 16 + l16;
                float vv = acc[mi][ni][r] + bcol[ni];
                vout[(size_t)row * DIM + col] = f2bf(vv);
                ss += vv * vv;
            }
            #pragma unroll
            for (int off = 8; off > 0; off >>= 1) ss += __shfl_down(ss, off);
            if (l16 == 0) atomicAdd(&rownorm[row], ss);
        }
}

// ---------------------------------------------------------------- phi tiles -> FP32 output
// 528 heavy blocks only. Each block: (a) one light tile (cols>rows, store-only)
// as prologue for blocks id<496 -> equal work, no early-retire imbalance;
// (b) 128x128 heavy tile, BK=64 (16 iters, half the barrier drains of BK=32),
// XOR chunk-swizzled LDS (kills the 8-way ds_read bank alias).
__global__ __launch_bounds__(256) void k_phi(
    const ushort* __restrict__ vn,
    const double* __restrict__ s_i, const double* __restrict__ s_j,
    const float* __restrict__ rowAtt, const float* __restrict__ rowRep,
    const float* __restrict__ massF, const int* __restrict__ flags,
    const float* __restrict__ rownorm, float* __restrict__ out)
{
    __shared__ ushort As[128 * 64], Bs[128 * 64];
    const int t = threadIdx.x;
    const int id = blockIdx.x;
    int r = 0;                           // decode id = r*(r+1)/2 + bj, bj<=r
    while (id >= ((r + 1) * (r + 2)) >> 1) ++r;
    const int bi = r, bj = id - ((r * (r + 1)) >> 1);
    const int m0 = bi * 128, n0 = bj * 128;
    const int wid = t >> 6, lane = t & 63;
    const int wm = wid >> 1, wn = wid & 1;
    const int quad = lane >> 4, l16 = lane & 15;
    const double LN4 = 1.3862943611198906;  // sigmoid(x)>0.8  <=>  x>ln4

    // ---- fused light tile (store-only prologue; col > row everywhere)
    if (id < 496) {
        int l = id, rl = 0;
        while (l >= 31 - rl) { l -= 31 - rl; ++rl; }
        const int lm0 = rl * 128, ln0 = (rl + 1 + l) * 128;
        float cmL[4]; double csjL[4]; int cfL[4]; int ccolL[4];
        #pragma unroll
        for (int ni = 0; ni < 4; ni++) {
            int col = ln0 + wn * 64 + ni * 16 + l16;
            ccolL[ni] = col; cmL[ni] = massF[col]; csjL[ni] = s_j[col]; cfL[ni] = flags[col];
        }
        #pragma unroll
        for (int mi = 0; mi < 4; mi++)
            #pragma unroll
            for (int rr = 0; rr < 4; rr++) {
                int row = lm0 + wm * 64 + mi * 16 + quad * 4 + rr;
                float  rR = rowRep[row];
                int    fi = flags[row];
                double si = s_i[row];
                size_t ob = (size_t)row * NROW;
                #pragma unroll
                for (int ni = 0; ni < 4; ni++) {
                    double x = si + csjL[ni];
                    bool   hit = (x > LN4) && ((fi & cfL[ni]) & 1);
                    float  conflict = 1.0f / (1.0f + expf(-(float)x));
                    out[ob + ccolL[ni]] = hit ? rR * conflict * cmL[ni] : 0.0f;
                }
            }
    }

    // ---- heavy column stats
    float  cm[4]; double csj[4]; int cf[4]; int ccol[4];
    #pragma unroll
    for (int ni = 0; ni < 4; ni++) {
        int col = n0 + wn * 64 + ni * 16 + l16;
        ccol[ni] = col; cm[ni] = massF[col]; csj[ni] = s_j[col]; cf[ni] = flags[col];
    }

    v4f acc[4][4];
    #pragma unroll
    for (int i = 0; i < 4; i++)
        #pragma unroll
        for (int j = 0; j < 4; j++) acc[i][j] = (v4f){0.f, 0.f, 0.f, 0.f};

    const int sr = t >> 3;              // staging row within 32-row round
    const int sc = t & 7;               // staging 16B chunk
    for (int k0 = 0; k0 < DIM; k0 += 64) {
        #pragma unroll
        for (int p = 0; p < 4; ++p) {
            int rr = p * 32 + sr;
            int ksw = ((sc ^ (rr & 7)) * 8);
            GLD16(&vn[(size_t)(m0 + rr) * DIM + k0 + ksw], &As[p * 2048 + wid * 512]);
            GLD16(&vn[(size_t)(n0 + rr) * DIM + k0 + ksw], &Bs[p * 2048 + wid * 512]);
        }
        __syncthreads();
        #pragma unroll
        for (int ks = 0; ks < 2; ++ks) {
            v8s af[4], bfr[4];
            #pragma unroll
            for (int mi = 0; mi < 4; mi++) {
                int row = wm * 64 + mi * 16 + l16;
                af[mi] = *(const v8s*)&As[row * 64 + (((ks * 4 + quad) ^ (l16 & 7)) * 8)];
            }
            #pragma unroll
            for (int ni = 0; ni < 4; ni++) {
                int row = wn * 64 + ni * 16 + l16;
                bfr[ni] = *(const v8s*)&Bs[row * 64 + (((ks * 4 + quad) ^ (l16 & 7)) * 8)];
            }
            #pragma unroll
            for (int mi = 0; mi < 4; mi++)
                #pragma unroll
                for (int ni = 0; ni < 4; ni++)
                    acc[mi][ni] = __builtin_amdgcn_mfma_f32_16x16x32_bf16(af[mi], bfr[ni], acc[mi][ni], 0, 0, 0);
        }
        __syncthreads();
    }

    float cinv[4];
    #pragma unroll
    for (int ni = 0; ni < 4; ni++)
        cinv[ni] = 1.0f / fmaxf(sqrtf(rownorm[ccol[ni]]), 1e-8f);

    #pragma unroll
    for (int mi = 0; mi < 4; mi++)
        #pragma unroll
        for (int rr = 0; rr < 4; rr++) {
            int row = m0 + wm * 64 + mi * 16 + quad * 4 + rr;
            float  rA = rowAtt[row], rR = rowRep[row];
            float  riv = 1.0f / fmaxf(sqrtf(rownorm[row]), 1e-8f);
            int    fi = flags[row];
            double si = s_i[row];
            size_t ob = (size_t)row * NROW;
            #pragma unroll
            for (int ni = 0; ni < 4; ni++) {
                int col = ccol[ni];
                double x = si + csj[ni];
                float conflict = 1.0f / (1.0f + expf(-(float)x));
                bool  chigh = x > LN4;
                bool  gate  = ((fi & cf[ni]) & 1) && (row != col);
                float Rv  = ((fi | cf[ni]) & 2) ? 0.0f : acc[mi][ni][rr] * riv * cinv[ni];
                float att = (col < row) ? rA * cm[ni] * (0.5f + 0.5f * Rv) : 0.0f;
                float ph  = gate ? (chigh ? rR * conflict * cm[ni] : att) : 0.0f;
                out[ob + col] = ph;   // FP32 output
            }
        }
}

extern "C" void kernel_launch(void* const* d_in, const int* in_sizes, int n_in,
                              void* d_out, int out_size, void* d_ws, size_t ws_size,
                              hipStream_t stream)
{
    const float* vecs      = (const float*)d_in[0];
    const float* mass      = (const float*)d_in[1];
    const float* hops      = (const float*)d_in[2];
    const int*   alive     = (const int*)d_in[3];
    const int*   is_photon = (const int*)d_in[4];
    const float* W         = (const float*)d_in[5];
    const float* Wb        = (const float*)d_in[6];
    const float* wci       = (const float*)d_in[7];
    const float* wcj       = (const float*)d_in[8];
    const float* bconf     = (const float*)d_in[9];
    const float* logc      = (const float*)d_in[10];
    const float* logG      = (const float*)d_in[11];

    char* ws = (char*)d_ws;
    double* s_i     = (double*)(ws);                 // 32 KB
    double* s_j     = (double*)(ws + 32768);         // 32 KB (holds s_j + b_conf)
    float*  rowAtt  = (float*)(ws + 65536);          // 16 KB
    float*  rowRep  = (float*)(ws + 81920);          // 16 KB
    float*  massF   = (float*)(ws + 98304);          // 16 KB
    int*    flagsA  = (int*)(ws + 114688);           // 16 KB
    float*  rownorm = (float*)(ws + 131072);         // 16 KB
    ushort* vn      = (ushort*)(ws + 147456);        // 8 MB (unnormalized v, bf16)

    k_stats<<<dim3(NROW / 4 + DIM / 4), dim3(256), 0, stream>>>(
        vecs, mass, hops, alive, is_photon, wci, wcj, logc, logG, bconf, W,
        s_i, s_j, rowAtt, rowRep, massF, flagsA, rownorm);
    k_proj<<<dim3(DIM / 64, NROW / 64), dim3(256), 0, stream>>>(vecs, W, Wb, vn, rownorm);
    k_phi<<<dim3(528), dim3(256), 0, stream>>>(
        vn, s_i, s_j, rowAtt, rowRep, massF, flagsA, rownorm, (float*)d_out);
}

// Round 2
// 167.614 us; speedup vs baseline: 1.1516x; 1.0999x over previous
//
#include <hip/hip_runtime.h>
#include <hip/hip_bf16.h>
#include <math.h>

#define NROW 4096
#define DIM  1024

typedef short v8s __attribute__((ext_vector_type(8)));
typedef float v4f __attribute__((ext_vector_type(4)));

#define GLD16(src, dst) __builtin_amdgcn_global_load_lds( \
    (const __attribute__((address_space(1))) void*)(src), \
    (__attribute__((address_space(3))) void*)(dst), 16, 0, 0)

__device__ __forceinline__ ushort f2bf(float f) {
    __hip_bfloat16 h = __float2bfloat16(f);
    union { __hip_bfloat16 h; ushort u; } x; x.h = h; return x.u;
}
__device__ __forceinline__ ushort4 cvt4(float4 a) {
    ushort4 r; r.x = f2bf(a.x); r.y = f2bf(a.y); r.z = f2bf(a.z); r.w = f2bf(a.w);
    return r;
}

// ---------------------------------------------------------------- merged row stats + W->bf16
// blocks [0,1024): rowstats on vecs rows (4/block) + bf16 shadow repack.
// blocks [1024,1280): W rows -> bf16 shadow (in place, second half of fp32 row).
__global__ __launch_bounds__(256) void k_stats(
    const float* __restrict__ vecs, const float* __restrict__ mass,
    const float* __restrict__ hops, const int* __restrict__ alive,
    const int* __restrict__ is_photon, const float* __restrict__ wci,
    const float* __restrict__ wcj, const float* __restrict__ logc,
    const float* __restrict__ logG, const float* __restrict__ bconf,
    const float* __restrict__ W,
    double* __restrict__ s_i, double* __restrict__ s_j,
    float* __restrict__ rowAtt, float* __restrict__ rowRep,
    float* __restrict__ massF, int* __restrict__ flags,
    float* __restrict__ rownorm)
{
    const int t = threadIdx.x;
    const int wid = t >> 6, lane = t & 63;

    if (blockIdx.x >= NROW / 4) {                  // ---- W convert part
        const int row = (blockIdx.x - NROW / 4) * 4 + wid;
        const float* wr = W + (size_t)row * DIM;
        ushort4 uc[4];
        #pragma unroll
        for (int q = 0; q < 4; ++q)
            uc[q] = cvt4(*(const float4*)&wr[lane * 4 + q * 256]);
        __syncthreads();
        ushort* wb = (ushort*)W + (size_t)row * 2048 + 1024;
        #pragma unroll
        for (int q = 0; q < 4; ++q)
            *(ushort4*)&wb[lane * 4 + q * 256] = uc[q];
        return;
    }

    const int row = blockIdx.x * 4 + wid;
    const float* vr = vecs + (size_t)row * DIM;
    double di = 0.0, dj = 0.0, ss = 0.0;
    ushort4 uc[4];
    #pragma unroll
    for (int q = 0; q < 4; ++q) {
        int base = lane * 4 + q * 256;             // coalesced: 64 lanes x 16B contiguous
        float4 pv = *(const float4*)&vr[base];
        float4 pi = *(const float4*)&wci[base];
        float4 pj = *(const float4*)&wcj[base];
        di += (double)pv.x * pi.x + (double)pv.y * pi.y + (double)pv.z * pi.z + (double)pv.w * pi.w;
        dj += (double)pv.x * pj.x + (double)pv.y * pj.y + (double)pv.z * pj.z + (double)pv.w * pj.w;
        ss += (double)pv.x * pv.x + (double)pv.y * pv.y + (double)pv.z * pv.z + (double)pv.w * pv.w;
        uc[q] = cvt4(pv);
    }
    __syncthreads();   // all fp32 reads drained before overwriting second halves
    ushort* vb = (ushort*)vecs + (size_t)row * 2048 + 1024;   // bf16 shadow of this row
    #pragma unroll
    for (int q = 0; q < 4; ++q)
        *(ushort4*)&vb[lane * 4 + q * 256] = uc[q];
    #pragma unroll
    for (int off = 32; off > 0; off >>= 1) {
        di += __shfl_down(di, off);
        dj += __shfl_down(dj, off);
        ss += __shfl_down(ss, off);
    }
    if (lane == 0) {
        double c  = fmax(exp((double)logc[0]), 1e-6);
        double G  = exp((double)logG[0]);
        double dl = (double)hops[row] / c;
        double lam = (is_photon[row] != 0) ? 1.0 : exp(-dl);
        double rs  = fmax(dl, 0.1);
        double cd  = (dl <= 1.0) ? 1.0 : exp(-dl + 1.0);
        double m   = (double)mass[row];
        s_i[row] = di;
        s_j[row] = dj + (double)bconf[0];                     // b_conf folded here
        rowAtt[row] = (float)(lam * G * m / (rs * rs) * cd);  // * m_j * (0.5+0.5R)
        rowRep[row] = (float)(-lam * m);                      // * conflict * m_j
        massF[row]  = (float)m;
        flags[row]  = ((alive[row] != 0) ? 1 : 0) | ((sqrt(ss) < 1e-8) ? 2 : 0);
        rownorm[row] = 0.0f;                                  // init for k_proj atomics
    }
}

// ---------------------------------------------------------------- v = vecs @ W^T + b
// 64x64 tiles, BK=64 -> grid (16,64) = 1024 blocks. Unchanged from round 1
// (known-passing); will surface in top-5 counters once k_phi drops below it.
__global__ __launch_bounds__(256) void k_proj(
    const float* __restrict__ A, const float* __restrict__ B,
    const float* __restrict__ bias, ushort* __restrict__ vout,
    float* __restrict__ rownorm)
{
    __shared__ ushort As[64 * 64], Bs[64 * 64];
    const int t = threadIdx.x;
    const int m0 = blockIdx.y * 64, n0 = blockIdx.x * 64;
    const int wid = t >> 6, lane = t & 63;
    const int wm = wid >> 1, wn = wid & 1;
    const int quad = lane >> 4, l16 = lane & 15;
    const ushort* Ab = (const ushort*)A;   // bf16 shadow: row r at r*2048+1024
    const ushort* Bb = (const ushort*)B;
    const int sr = t >> 3;                 // staging row within 32-row round
    const int sc = t & 7;                  // staging 16B chunk
    v4f acc[2][2];
    #pragma unroll
    for (int i = 0; i < 2; i++)
        #pragma unroll
        for (int j = 0; j < 2; j++) acc[i][j] = (v4f){0.f, 0.f, 0.f, 0.f};

    for (int k0 = 0; k0 < DIM; k0 += 64) {
        #pragma unroll
        for (int p = 0; p < 2; ++p) {
            int r = p * 32 + sr;
            int ksw = ((sc ^ (r & 7)) * 8);
            GLD16(&Ab[(size_t)(m0 + r) * 2048 + 1024 + k0 + ksw], &As[p * 2048 + wid * 512]);
            GLD16(&Bb[(size_t)(n0 + r) * 2048 + 1024 + k0 + ksw], &Bs[p * 2048 + wid * 512]);
        }
        __syncthreads();
        #pragma unroll
        for (int ks = 0; ks < 2; ++ks) {
            v8s af[2], bfr[2];
            #pragma unroll
            for (int mi = 0; mi < 2; mi++) {
                int row = wm * 32 + mi * 16 + l16;
                af[mi] = *(const v8s*)&As[row * 64 + (((ks * 4 + quad) ^ (l16 & 7)) * 8)];
            }
            #pragma unroll
            for (int ni = 0; ni < 2; ni++) {
                int row = wn * 32 + ni * 16 + l16;
                bfr[ni] = *(const v8s*)&Bs[row * 64 + (((ks * 4 + quad) ^ (l16 & 7)) * 8)];
            }
            #pragma unroll
            for (int mi = 0; mi < 2; mi++)
                #pragma unroll
                for (int ni = 0; ni < 2; ni++)
                    acc[mi][ni] = __builtin_amdgcn_mfma_f32_16x16x32_bf16(af[mi], bfr[ni], acc[mi][ni], 0, 0, 0);
        }
        __syncthreads();
    }
    float bcol[2];
    #pragma unroll
    for (int ni = 0; ni < 2; ni++) bcol[ni] = bias[n0 + wn * 32 + ni * 16 + l16];
    #pragma unroll
    for (int mi = 0; mi < 2; mi++)
        #pragma unroll
        for (int r = 0; r < 4; r++) {
            int row = m0 + wm * 32 + mi * 16 + quad * 4 + r;
            float ss = 0.0f;
            #pragma unroll
            for (int ni = 0; ni < 2; ni++) {
                int col = n0 + wn * 32 + ni * 16 + l16;
                float vv = acc[mi][ni][r] + bcol[ni];
                vout[(size_t)row * DIM + col] = f2bf(vv);
                ss += vv * vv;
            }
            #pragma unroll
            for (int off = 8; off > 0; off >>= 1) ss += __shfl_down(ss, off);
            if (l16 == 0) atomicAdd(&rownorm[row], ss);
        }
}

// ---------------------------------------------------------------- phi tiles -> FP32 output
// 64x64 tiles over the lower triangle incl diagonal: 64*65/2 = 2080 blocks
// (8.1/CU vs 2.06 before -- the round-1 counters showed pure under-occupancy:
// Occ 13%, Mfma 9%, VALU 37%, nothing saturated). Strict-lower blocks also
// compute the transposed upper (light) tile as a store-only prologue that
// overlaps the first staging loads. VALU diet: __expf + v_rcp sigmoid, gates
// folded into per-row/per-col multiplicative constants; gate compare (x>ln4)
// kept in double, identical to the passing kernel.
__global__ __launch_bounds__(256, 5) void k_phi(
    const ushort* __restrict__ vn,
    const double* __restrict__ s_i, const double* __restrict__ s_j,
    const float* __restrict__ rowAtt, const float* __restrict__ rowRep,
    const float* __restrict__ massF, const int* __restrict__ flags,
    const float* __restrict__ rownorm, float* __restrict__ out)
{
    __shared__ ushort As[64 * 64], Bs[64 * 64];
    const int t = threadIdx.x;
    const int id = blockIdx.x;
    int r = (int)((sqrtf(8.0f * (float)id + 1.0f) - 1.0f) * 0.5f);
    while ((((r + 1) * (r + 2)) >> 1) <= id) ++r;
    while (((r * (r + 1)) >> 1) > id) --r;
    const int bi = r, bj = id - ((r * (r + 1)) >> 1);   // bi >= bj
    const bool diag = (bi == bj);
    const int m0 = bi * 64, n0 = bj * 64;
    const int wid = t >> 6, lane = t & 63;
    const int wm = wid >> 1, wn = wid & 1;
    const int quad = lane >> 4, l16 = lane & 15;
    const int sr = t >> 3, sc = t & 7;
    const double LN4 = 1.3862943611198906;  // sigmoid(x)>0.8  <=>  x>ln4

    // ---- issue first K-tile staging immediately (light tile overlaps it)
    #pragma unroll
    for (int p = 0; p < 2; ++p) {
        int rr = p * 32 + sr;
        int ksw = (sc ^ (rr & 7)) * 8;
        GLD16(&vn[(size_t)(m0 + rr) * DIM + ksw], &As[p * 2048 + wid * 512]);
        GLD16(&vn[(size_t)(n0 + rr) * DIM + ksw], &Bs[p * 2048 + wid * 512]);
    }

    // ---- fused light tile (transposed position: rows from bj-tile, cols from
    //      bi-tile; col > row everywhere). Store-only, overlaps loads above.
    if (!diag) {
        double csjL[2]; float cmL[2]; int colL[2];
        #pragma unroll
        for (int ni = 0; ni < 2; ni++) {
            int col = m0 + wn * 32 + ni * 16 + l16;
            colL[ni] = col;
            csjL[ni] = s_j[col];
            cmL[ni]  = (flags[col] & 1) ? massF[col] : 0.f;
        }
        #pragma unroll
        for (int mi = 0; mi < 2; mi++)
            #pragma unroll
            for (int rr = 0; rr < 4; rr++) {
                int row = n0 + wm * 32 + mi * 16 + quad * 4 + rr;
                double si = s_i[row];
                float  rRm = (flags[row] & 1) ? rowRep[row] : 0.f;
                size_t ob = (size_t)row * NROW;
                #pragma unroll
                for (int ni = 0; ni < 2; ni++) {
                    double x = si + csjL[ni];
                    float v = 0.f;
                    if (x > LN4) {
                        float e = __expf(-(float)x);
                        v = rRm * cmL[ni] * __builtin_amdgcn_rcpf(1.0f + e);
                    }
                    out[ob + colL[ni]] = v;
                }
            }
    }

    // ---- heavy column stats (load early, overlap with staging latency)
    double csjH[2]; float cmn[2], cc[2]; int colH[2];
    #pragma unroll
    for (int ni = 0; ni < 2; ni++) {
        int col = n0 + wn * 32 + ni * 16 + l16;
        int cf = flags[col];
        float cma = (cf & 1) ? massF[col] : 0.f;
        colH[ni] = col;
        csjH[ni] = s_j[col];
        cmn[ni]  = cma;
        cc[ni]   = (cf & 2) ? 0.f
                 : cma * __builtin_amdgcn_rcpf(fmaxf(sqrtf(rownorm[col]), 1e-8f));
    }

    v4f acc[2][2];
    #pragma unroll
    for (int i = 0; i < 2; i++)
        #pragma unroll
        for (int j = 0; j < 2; j++) acc[i][j] = (v4f){0.f, 0.f, 0.f, 0.f};

    __syncthreads();
    for (int k0 = 0; k0 < DIM; k0 += 64) {
        #pragma unroll
        for (int ks = 0; ks < 2; ++ks) {
            v8s af[2], bfr[2];
            #pragma unroll
            for (int mi = 0; mi < 2; mi++) {
                int row = wm * 32 + mi * 16 + l16;
                af[mi] = *(const v8s*)&As[row * 64 + (((ks * 4 + quad) ^ (l16 & 7)) * 8)];
            }
            #pragma unroll
            for (int ni = 0; ni < 2; ni++) {
                int row = wn * 32 + ni * 16 + l16;
                bfr[ni] = *(const v8s*)&Bs[row * 64 + (((ks * 4 + quad) ^ (l16 & 7)) * 8)];
            }
            #pragma unroll
            for (int mi = 0; mi < 2; mi++)
                #pragma unroll
                for (int ni = 0; ni < 2; ni++)
                    acc[mi][ni] = __builtin_amdgcn_mfma_f32_16x16x32_bf16(af[mi], bfr[ni], acc[mi][ni], 0, 0, 0);
        }
        if (k0 + 64 < DIM) {
            __syncthreads();          // reads drained before restage
            int k1 = k0 + 64;
            #pragma unroll
            for (int p = 0; p < 2; ++p) {
                int rr = p * 32 + sr;
                int ksw = (sc ^ (rr & 7)) * 8;
                GLD16(&vn[(size_t)(m0 + rr) * DIM + k1 + ksw], &As[p * 2048 + wid * 512]);
                GLD16(&vn[(size_t)(n0 + rr) * DIM + k1 + ksw], &Bs[p * 2048 + wid * 512]);
            }
            __syncthreads();
        }
    }

    // ---- heavy epilogue: 8 rows x 2 cols per thread
    #pragma unroll
    for (int mi = 0; mi < 2; mi++)
        #pragma unroll
        for (int rr = 0; rr < 4; rr++) {
            int row = m0 + wm * 32 + mi * 16 + quad * 4 + rr;
            int fi = flags[row];
            float rA  = rowAtt[row];
            float riv = __builtin_amdgcn_rcpf(fmaxf(sqrtf(rownorm[row]), 1e-8f));
            float a1  = (fi & 1) ? 0.5f * rA : 0.f;                 // alive gate folded
            float a2  = ((fi & 3) == 1) ? 0.5f * rA * riv : 0.f;    // + zero-norm gate
            float rRm = (fi & 1) ? rowRep[row] : 0.f;
            double si = s_i[row];
            size_t ob = (size_t)row * NROW;
            #pragma unroll
            for (int ni = 0; ni < 2; ni++) {
                double x = si + csjH[ni];
                float  acv = acc[mi][ni][rr];
                float  att = fmaf(a2 * cc[ni], acv, a1 * cmn[ni]);
                float  e   = __expf(-(float)x);
                float  rep = rRm * cmn[ni] * __builtin_amdgcn_rcpf(1.0f + e);
                float  v   = (x > LN4) ? rep : att;
                if (diag) {
                    int col = colH[ni];
                    if (col > row) v = (x > LN4) ? rep : 0.f;   // upper half: rep-only
                    if (col == row) v = 0.f;                    // diagonal zero
                }
                out[ob + colH[ni]] = v;
            }
        }
}

extern "C" void kernel_launch(void* const* d_in, const int* in_sizes, int n_in,
                              void* d_out, int out_size, void* d_ws, size_t ws_size,
                              hipStream_t stream)
{
    const float* vecs      = (const float*)d_in[0];
    const float* mass      = (const float*)d_in[1];
    const float* hops      = (const float*)d_in[2];
    const int*   alive     = (const int*)d_in[3];
    const int*   is_photon = (const int*)d_in[4];
    const float* W         = (const float*)d_in[5];
    const float* Wb        = (const float*)d_in[6];
    const float* wci       = (const float*)d_in[7];
    const float* wcj       = (const float*)d_in[8];
    const float* bconf     = (const float*)d_in[9];
    const float* logc      = (const float*)d_in[10];
    const float* logG      = (const float*)d_in[11];

    char* ws = (char*)d_ws;
    double* s_i     = (double*)(ws);                 // 32 KB
    double* s_j     = (double*)(ws + 32768);         // 32 KB (holds s_j + b_conf)
    float*  rowAtt  = (float*)(ws + 65536);          // 16 KB
    float*  rowRep  = (float*)(ws + 81920);          // 16 KB
    float*  massF   = (float*)(ws + 98304);          // 16 KB
    int*    flagsA  = (int*)(ws + 114688);           // 16 KB
    float*  rownorm = (float*)(ws + 131072);         // 16 KB
    ushort* vn      = (ushort*)(ws + 147456);        // 8 MB (unnormalized v, bf16)

    k_stats<<<dim3(NROW / 4 + DIM / 4), dim3(256), 0, stream>>>(
        vecs, mass, hops, alive, is_photon, wci, wcj, logc, logG, bconf, W,
        s_i, s_j, rowAtt, rowRep, massF, flagsA, rownorm);
    k_proj<<<dim3(DIM / 64, NROW / 64), dim3(256), 0, stream>>>(vecs, W, Wb, vn, rownorm);
    k_phi<<<dim3(2080), dim3(256), 0, stream>>>(
        vn, s_i, s_j, rowAtt, rowRep, massF, flagsA, rownorm, (float*)d_out);
}